// Round 1
// 458.494 us; speedup vs baseline: 1.0151x; 1.0151x over previous
//
#include <hip/hip_runtime.h>

// Problem constants (reference: D=4096, K=128, B=4, S=4096)
#define DD 4096
#define KK 128
#define MAXHC 48      // cap on ceil(max_bucket_size/2); mean bucket=32, std 5.6 -> 96 is >11 sigma
#define XROW 4100     // padded LDS row stride (floats); 4100*4 is 16B-aligned; [4096] is sentinel
#define QVC_OFF 24832 // byte offset of qvC pack in ws (16B aligned, past perm2+maxh)

// ---------------------------------------------------------------------------
// Setup kernel (2 blocks).
// Block 0: build thread-major padded permutation in ws (unchanged layout):
//   perm2 (ushort): iteration i, thread tid -> offset (i>>1)*512 + tid*2 + (i&1)
//   Bucket c split round-robin between threads 2c (half 0) and 2c+1.
//   Pads hold index DD (=4096) -> zeroed LDS sentinel in the main kernel.
// Block 1: pack qvC[c4*128 + k] = {qv[(4c4+i)*128 + k], i=0..3} (float4, 64 KB)
//   so phase 2 of vq_main reads qv as coalesced float4 instead of 4x scalar.
// ---------------------------------------------------------------------------
__global__ void vq_build(const float* __restrict__ qv,
                         const int* __restrict__ assign,
                         unsigned short* __restrict__ perm2,
                         int* __restrict__ maxh,
                         float4* __restrict__ qvC) {
    const int tid = threadIdx.x;

    if (blockIdx.x == 1) {
        // qv rows 0..127 (64 KB) -> c4-major float4 pack; reads 256B-coalesced.
        for (int idx = tid; idx < 4096; idx += 256) {
            const int c4 = idx >> 7;
            const int k  = idx & (KK - 1);
            float4 v;
            v.x = qv[(4 * c4 + 0) * KK + k];
            v.y = qv[(4 * c4 + 1) * KK + k];
            v.z = qv[(4 * c4 + 2) * KK + k];
            v.w = qv[(4 * c4 + 3) * KK + k];
            qvC[idx] = v;
        }
        return;
    }

    __shared__ int cnt[KK];
    __shared__ int off[KK];

    if (tid < KK) cnt[tid] = 0;
    for (int i = tid; i < MAXHC * 256; i += 256)
        perm2[i] = (unsigned short)DD;
    __syncthreads();

    for (int j = tid; j < DD; j += 256)
        atomicAdd(&cnt[assign[j]], 1);
    __syncthreads();

    if (tid == 0) {
        int m = 0;
        for (int c = 0; c < KK; ++c) {
            off[c] = 0;
            int h = (cnt[c] + 1) >> 1;
            if (h > m) m = h;
        }
        *maxh = (m < MAXHC) ? m : MAXHC;
    }
    __syncthreads();

    for (int j = tid; j < DD; j += 256) {
        const int c = assign[j];
        const int p = atomicAdd(&off[c], 1);
        const int i = p >> 1;
        const int th = 2 * c + (p & 1);
        if (i < MAXHC)
            perm2[(i >> 1) * 512 + th * 2 + (i & 1)] = (unsigned short)j;
    }
}

// ---------------------------------------------------------------------------
// Main kernel: one block per TWO token rows (amortize pu/assign/bias/qv 2x).
//   out[t,d] = qm[t, a[d]] + bias[d],  qm[t,k] = sum_c xs[t,c]*QV[c,k],
//   xs[t,c] = sum_{j: a[j]==c} x[t,j]  (atomic-free via perm2 gather).
// Phase 2: one thread per (token,k): 32 coalesced float4 qvC loads + 128 FMA,
//   no cross-thread reduce, single barrier. qm stored interleaved [k][token]
//   so phase 3 gathers one float2 per output pair.
// ---------------------------------------------------------------------------
__global__ __launch_bounds__(256) void vq_main(
    const float* __restrict__ x,        // [T, D]
    const int*   __restrict__ assign,   // [D]
    const float* __restrict__ bias,     // [D]
    const unsigned int* __restrict__ pu,// perm2 as packed uint pairs
    const int* __restrict__ maxh,
    const float4* __restrict__ qvC,     // packed [32][128] float4
    float* __restrict__ out)            // [T, D]
{
    __shared__ float xl[2 * XROW];      // two staged rows + sentinels
    __shared__ float xs[2 * KK];        // bucket sums per token (planar)
    __shared__ float qm2[2 * KK];       // qm interleaved: qm2[2k+token]

    const int t0  = blockIdx.x * 2;
    const int tid = threadIdx.x;

    // Phase 0: stage both rows into LDS, coalesced float4 (conflict-free b128).
    const float4* r0 = reinterpret_cast<const float4*>(x + (size_t)t0 * DD);
    const float4* r1 = reinterpret_cast<const float4*>(x + (size_t)(t0 + 1) * DD);
    float4* xl40 = reinterpret_cast<float4*>(xl);
    float4* xl41 = reinterpret_cast<float4*>(xl + XROW);
    #pragma unroll
    for (int i = 0; i < 4; ++i) {
        xl40[tid + i * 256] = r0[tid + i * 256];
        xl41[tid + i * 256] = r1[tid + i * 256];
    }
    if (tid == 0) { xl[DD] = 0.0f; xl[XROW + DD] = 0.0f; }
    __syncthreads();

    // Phase 1: bucket sums, no atomics. Thread tid = 2c+h owns half h of bucket c.
    {
        const int mh2 = (*maxh + 1) >> 1;          // packed-pair iterations (~13)
        float a0 = 0.0f, a1 = 0.0f;
        for (int ii = 0; ii < mh2; ++ii) {
            const unsigned int pp = pu[ii * 256 + tid];  // coalesced, L1-hit
            const int i0 = pp & 0xFFFFu;
            const int i1 = pp >> 16;
            a0 += xl[i0];
            a0 += xl[i1];
            a1 += xl[XROW + i0];
            a1 += xl[XROW + i1];
        }
        a0 += __shfl_xor(a0, 1);                   // combine the two halves
        a1 += __shfl_xor(a1, 1);
        if ((tid & 1) == 0) {
            xs[tid >> 1]      = a0;
            xs[KK + (tid >> 1)] = a1;
        }
    }
    __syncthreads();

    // Phase 2: thread (tt = tid>>7, k = tid&127) computes qm[tt][k] alone.
    // qvC loads: 64 lanes x consecutive k -> 1KB contiguous per wave inst.
    {
        const int k  = tid & (KK - 1);
        const int tt = tid >> 7;
        const float4* xs4 = reinterpret_cast<const float4*>(xs + tt * KK);
        float ax = 0.f, ay = 0.f, az = 0.f, aw = 0.f;   // 4 independent chains
        #pragma unroll 8
        for (int c4 = 0; c4 < 32; ++c4) {
            const float4 q = qvC[c4 * KK + k];
            const float4 v = xs4[c4];                   // uniform -> LDS broadcast
            ax += q.x * v.x;
            ay += q.y * v.y;
            az += q.z * v.z;
            aw += q.w * v.w;
        }
        qm2[2 * k + tt] = (ax + ay) + (az + aw);
    }
    __syncthreads();

    // Phase 3: out[t,d] = qm[t,a[d]] + bias[d]; one b64 gather serves both tokens.
    const int4*   a4   = reinterpret_cast<const int4*>(assign);
    const float4* b4   = reinterpret_cast<const float4*>(bias);
    const float2* qmf2 = reinterpret_cast<const float2*>(qm2);
    float4* o0 = reinterpret_cast<float4*>(out + (size_t)t0 * DD);
    float4* o1 = reinterpret_cast<float4*>(out + (size_t)(t0 + 1) * DD);
    #pragma unroll
    for (int i = 0; i < 4; ++i) {
        const int idx = tid + i * 256;
        const int4   a = a4[idx];
        const float4 b = b4[idx];
        const float2 qx = qmf2[a.x];
        const float2 qy = qmf2[a.y];
        const float2 qz = qmf2[a.z];
        const float2 qw = qmf2[a.w];
        float4 s0, s1;
        s0.x = qx.x + b.x;  s1.x = qx.y + b.x;
        s0.y = qy.x + b.y;  s1.y = qy.y + b.y;
        s0.z = qz.x + b.z;  s1.z = qz.y + b.z;
        s0.w = qw.x + b.w;  s1.w = qw.y + b.w;
        o0[idx] = s0;
        o1[idx] = s1;
    }
}

extern "C" void kernel_launch(void* const* d_in, const int* in_sizes, int n_in,
                              void* d_out, int out_size, void* d_ws, size_t ws_size,
                              hipStream_t stream) {
    const float* x      = (const float*)d_in[0];  // [B,S,D] fp32
    const float* qv     = (const float*)d_in[1];  // [D,K]   fp32
    const int*   assign = (const int*)d_in[2];    // [D]     int32
    const float* bias   = (const float*)d_in[3];  // [D]     fp32
    float*       out    = (float*)d_out;

    // ws layout: [perm2: 24576 B][maxh: 4 B][pad][qvC: 65536 B @ QVC_OFF]
    unsigned short* perm2 = (unsigned short*)d_ws;
    int*    maxh = (int*)((char*)d_ws + MAXHC * 256 * sizeof(unsigned short));
    float4* qvC  = (float4*)((char*)d_ws + QVC_OFF);

    const int T = in_sizes[0] / DD;               // 16384 tokens

    vq_build<<<dim3(2), dim3(256), 0, stream>>>(qv, assign, perm2, maxh, qvC);
    vq_main<<<dim3(T / 2), dim3(256), 0, stream>>>(
        x, assign, bias, (const unsigned int*)perm2, maxh, qvC, out);
}